// Round 1
// baseline (927.118 us; speedup 1.0000x reference)
//
#include <hip/hip_runtime.h>

// Problem constants (from reference setup_inputs)
constexpr int T = 16;       // tables
constexpr int E = 200000;   // rows per table
constexpr int D = 64;       // embedding dim
constexpr int B = 4096;     // batch
constexpr int L = 20;       // fixed bag length (still read offsets for safety)

// FBGEMM-style shape: ONE bag per wave, one float of the D=64 row per lane.
//  - each gather is a single global_load_dword: 64 lanes x 4B = one full
//    256B row, perfectly coalesced -> one row request per VMEM instruction
//  - bag/offsets/indices are wave-uniform -> scalar (s_load) path, SGPR row
//    bases; no vector-load redundancy, near-zero per-gather VALU
//  - ~32 VGPRs/lane -> 8 waves/SIMD; 32 waves/CU x 20 in-flight rows each
//    gives enormous memory-level parallelism vs the old 4-bag/wave scheme
__global__ __launch_bounds__(256) void tbe_pooled_fwd(
    const int*   __restrict__ indices,   // [T*B*L]
    const int*   __restrict__ offsets,   // [T*B+1]
    const float* __restrict__ weights,   // [T, E, D]
    float*       __restrict__ out)       // [B, T*D]
{
    const int lane = threadIdx.x & 63;
    const int wave = threadIdx.x >> 6;

    // Force wave-uniformity so the compiler keeps bag math + index loads on
    // the scalar path (s_load / SALU).
    const int bag = __builtin_amdgcn_readfirstlane(blockIdx.x * 4 + wave);
    const int t   = bag >> 12;           // bag / B   (B = 4096)
    const int b   = bag & (B - 1);       // bag % B

    const int start = offsets[bag];      // uniform -> s_load
    const int end   = offsets[bag + 1];
    const int n     = end - start;

    const float* tbl = weights + (size_t)t * (E * D);

    float acc = 0.f;

    if (n == L) {
        // Fast path: 20 scalar index loads, then 20 independent full-row
        // gathers in flight per wave.
        int idx[L];
#pragma unroll
        for (int l = 0; l < L; ++l)
            idx[l] = indices[start + l];             // uniform -> s_load
#pragma unroll
        for (int l = 0; l < L; ++l)
            acc += tbl[(uint32_t)idx[l] * D + lane]; // SGPR base + lane*4
    } else {
        for (int l = 0; l < n; ++l) {
            const int i = indices[start + l];
            acc += tbl[(uint32_t)i * D + lane];
        }
    }

    // out[b, t*D + lane] -- 64 lanes x 4B = 256B contiguous store per wave
    out[(size_t)b * (T * D) + t * D + lane] = acc;
}

extern "C" void kernel_launch(void* const* d_in, const int* in_sizes, int n_in,
                              void* d_out, int out_size, void* d_ws, size_t ws_size,
                              hipStream_t stream) {
    const int*   indices = (const int*)  d_in[0];
    const int*   offsets = (const int*)  d_in[1];
    const float* weights = (const float*)d_in[2];
    float*       out     = (float*)      d_out;

    const int num_bags = T * B;              // 65536 bags, 1 per wave
    const int blocks   = num_bags / 4;       // 4 waves (bags) per 256-thr block

    tbe_pooled_fwd<<<blocks, 256, 0, stream>>>(indices, offsets, weights, out);
}